// Round 10
// baseline (315.759 us; speedup 1.0000x reference)
//
#include <hip/hip_runtime.h>
#include <hip/hip_bf16.h>
#include <cstdint>
#include <cstddef>

// MoE: T=4096, D=1024, H=2816, E=8, top-2, SwiGLU.
// R10: register-transpose prep (no LDS/conflicts), atomic ffn2 epilogue
//      (drops combine + obuf). K1 = gate || prep(w1,w3); K3 = ffn1 || prep(w2).

#define Tt 4096
#define Dd 1024
#define Hh 2816
#define Ee 8
#define NVT 71            // max sum_e ceil(ne/128)
#define NTILE 5632        // Ee*(Dd/64)*(Hh/64) per weight matrix
#define FFN1_BLKS ((Hh / 128) * NVT)  // 1562

typedef __bf16 bf16_t;
typedef __bf16 bf16x4 __attribute__((ext_vector_type(4)));
typedef __bf16 bf16x8 __attribute__((ext_vector_type(8)));
typedef float f32x4 __attribute__((ext_vector_type(4)));

__device__ __forceinline__ void gload16(const void* g, void* l) {
  __builtin_amdgcn_global_load_lds(
      (__attribute__((address_space(1))) void*)(void*)(uintptr_t)g,
      (__attribute__((address_space(3))) void*)l, 16, 0, 0);
}
#define WAIT_VM0() asm volatile("s_waitcnt vmcnt(0)" ::: "memory")

// ---- prep tile role: 64x64 fp32 -> bf16 transposed, pure registers --------
// Thread t: 4x4 sub-block at rows (t&15)*4.., cols (t>>4)*4..
// Loads: 4x float4 (64B segments). Stores: 4x bf16x4 (128B segments). No LDS.
__device__ __forceinline__ void prep_tile(const float* __restrict__ src,
                                          bf16_t* __restrict__ dst, int R, int C,
                                          int tbid, int tid) {
  const int tilesC = C / 64, tilesR = R / 64;
  const int e = tbid / (tilesR * tilesC);
  const int rem = tbid % (tilesR * tilesC);
  const int r0 = (rem / tilesC) * 64, c0 = (rem % tilesC) * 64;
  src += (size_t)e * R * C + (size_t)r0 * C + c0;
  dst += (size_t)e * R * C + (size_t)c0 * R + r0;
  const int tr = (tid & 15) * 4;
  const int tc = (tid >> 4) * 4;
  f32x4 v[4];
#pragma unroll
  for (int j = 0; j < 4; ++j)
    v[j] = *(const f32x4*)(src + (size_t)(tr + j) * C + tc);
#pragma unroll
  for (int k = 0; k < 4; ++k) {
    bf16x4 w;
    w[0] = (__bf16)v[0][k]; w[1] = (__bf16)v[1][k];
    w[2] = (__bf16)v[2][k]; w[3] = (__bf16)v[3][k];
    *(bf16x4*)(dst + (size_t)(tc + k) * R + tr) = w;
  }
}

// ---------------- K1: gate (blocks 0..127) || prep w1/w3 -------------------
__global__ __launch_bounds__(256) void gate_prep13_kernel(
    const float* __restrict__ x, const float* __restrict__ gw_g,
    const float* __restrict__ w1, const float* __restrict__ w3,
    int* __restrict__ counts, int* __restrict__ perm, float* __restrict__ topkw,
    bf16_t* __restrict__ xb, bf16_t* __restrict__ w1t, bf16_t* __restrict__ w3t) {
  const int tid = threadIdx.x;
  const int bid = blockIdx.x;
  if (bid >= 128) {
    const int pbid = bid - 128;
    if (pbid < NTILE) prep_tile(w1, w1t, Dd, Hh, pbid, tid);
    else prep_tile(w3, w3t, Dd, Hh, pbid - NTILE, tid);
    return;
  }
  __shared__ float gw[Dd * 9];
  for (int i = tid; i < Dd * Ee; i += 256) gw[(i >> 3) * 9 + (i & 7)] = gw_g[i];
  __syncthreads();
  const int tok = bid * 32 + (tid >> 3);
  const int part = tid & 7;
  const float* xr = x + (size_t)tok * Dd;
  float acc[Ee];
#pragma unroll
  for (int e = 0; e < Ee; ++e) acc[e] = 0.f;
  for (int i = 0; i < 32; ++i) {
    const int d = i * 32 + part * 4;
    const float4 xv = *(const float4*)(xr + d);
    bf16x4 bv; bv[0] = (__bf16)xv.x; bv[1] = (__bf16)xv.y; bv[2] = (__bf16)xv.z; bv[3] = (__bf16)xv.w;
    *(bf16x4*)(xb + (size_t)tok * Dd + d) = bv;
    const float xs[4] = {xv.x, xv.y, xv.z, xv.w};
#pragma unroll
    for (int j = 0; j < 4; ++j)
#pragma unroll
      for (int e = 0; e < Ee; ++e) acc[e] += xs[j] * gw[(d + j) * 9 + e];
  }
#pragma unroll
  for (int s = 1; s < 8; s <<= 1)
#pragma unroll
    for (int e = 0; e < Ee; ++e) acc[e] += __shfl_xor(acc[e], s, 64);
  if (part == 0) {
    int i0 = 0; float v0 = acc[0];
#pragma unroll
    for (int e = 1; e < Ee; ++e) if (acc[e] > v0) { v0 = acc[e]; i0 = e; }
    int i1 = -1; float v1 = -1e30f;
#pragma unroll
    for (int e = 0; e < Ee; ++e)
      if (e != i0 && acc[e] > v1) { v1 = acc[e]; i1 = e; }
    const float w0 = 1.f / (1.f + __expf(v1 - v0));
    topkw[tok * 2 + 0] = w0;
    topkw[tok * 2 + 1] = 1.f - w0;
    const int p0 = atomicAdd(&counts[i0], 1);
    perm[i0 * Tt + p0] = tok * 2 + 0;
    const int p1 = atomicAdd(&counts[i1], 1);
    perm[i1 * Tt + p1] = tok * 2 + 1;
  }
}

__global__ void scan_kernel(const int* __restrict__ counts, int* __restrict__ offs,
                            int* __restrict__ ts) {
  if (threadIdx.x == 0) {
    int s = 0, t = 0;
    for (int e = 0; e < Ee; ++e) {
      offs[e] = s; ts[e] = t;
      s += counts[e]; t += (counts[e] + 127) >> 7;
    }
    offs[Ee] = s; ts[Ee] = t;
  }
}

// ---------------- K3: fused ffn1 (blocks 0..1561) || prep w2 ----------------
__global__ __launch_bounds__(256, 2) void ffn1_prep2_kernel(
    const bf16_t* __restrict__ xb, const bf16_t* __restrict__ w1t,
    const bf16_t* __restrict__ w3t, const float* __restrict__ w2,
    const int* __restrict__ perm, const int* __restrict__ counts,
    const int* __restrict__ offs, const int* __restrict__ ts,
    bf16_t* __restrict__ hbuf, bf16_t* __restrict__ w2t) {
  const int tid = threadIdx.x;
  const int obid = blockIdx.x;
  if (obid >= FFN1_BLKS) {
    prep_tile(w2, w2t, Hh, Dd, obid - FFN1_BLKS, tid);
    return;
  }
  __shared__ __align__(16) bf16_t As[128 * 64];
  __shared__ __align__(16) bf16_t B1s[128 * 64];
  __shared__ __align__(16) bf16_t B3s[128 * 64];

  const int G = FFN1_BLKS;
  const int xcd = obid & 7, seq = obid >> 3;
  const int q = G >> 3, r = G & 7;
  const int lin = (xcd < r ? xcd * (q + 1) : r * (q + 1) + (xcd - r) * q) + seq;
  const int vt = lin % NVT;
  const int nb = lin / NVT;
  if (vt >= ts[Ee]) return;
  int e = 0;
#pragma unroll
  for (int i = 1; i < Ee; ++i) if (vt >= ts[i]) e = i;
  const int ne = counts[e];
  const int m0 = (vt - ts[e]) * 128;
  const int h0 = nb * 128;
  const int hb = offs[e];

  const int lane = tid & 63;
  const int wid = tid >> 6;

  const int scol = ((tid & 7) << 3) ^ (((tid >> 3) & 7) << 3);
  uint32_t aoff[4], boff[4];
#pragma unroll
  for (int i = 0; i < 4; ++i) {
    const int row = i * 32 + (tid >> 3);
    const int gr = m0 + row;
    const int rec = (gr < ne) ? perm[e * Tt + gr] : 0;
    aoff[i] = (uint32_t)((rec >> 1) * Dd + scol);
    boff[i] = (uint32_t)((h0 + row) * Dd + scol);
  }
  const bf16_t* w1e = w1t + (size_t)e * Hh * Dd;
  const bf16_t* w3e = w3t + (size_t)e * Hh * Dd;

  f32x4 acc1[4][4], acc3[4][4];
#pragma unroll
  for (int m = 0; m < 4; ++m)
#pragma unroll
    for (int n = 0; n < 4; ++n) {
      acc1[m][n] = (f32x4){0.f, 0.f, 0.f, 0.f};
      acc3[m][n] = (f32x4){0.f, 0.f, 0.f, 0.f};
    }

  const int wm = wid >> 1, wn = wid & 1;
  int aoffm[4], boffn[4], koff[2];
#pragma unroll
  for (int m = 0; m < 4; ++m) aoffm[m] = (wm * 64 + m * 16 + (lane & 15)) * 64;
#pragma unroll
  for (int n = 0; n < 4; ++n) boffn[n] = (wn * 64 + n * 16 + (lane & 15)) * 64;
#pragma unroll
  for (int kk = 0; kk < 2; ++kk)
    koff[kk] = (kk * 32 + (lane >> 4) * 8) ^ ((lane & 7) << 3);

  for (int kt = 0; kt < Dd / 64; ++kt) {
    const int d0 = kt * 64;
    __syncthreads();
#pragma unroll
    for (int i = 0; i < 4; ++i) {
      const int lb = (i * 256 + tid) * 8;
      gload16(xb + aoff[i] + d0, As + lb);
      gload16(w1e + boff[i] + d0, B1s + lb);
      gload16(w3e + boff[i] + d0, B3s + lb);
    }
    WAIT_VM0();
    __syncthreads();
#pragma unroll
    for (int kk = 0; kk < 2; ++kk) {
      bf16x8 a[4], b1[4], b3[4];
#pragma unroll
      for (int m = 0; m < 4; ++m) a[m] = *(const bf16x8*)(As + aoffm[m] + koff[kk]);
#pragma unroll
      for (int n = 0; n < 4; ++n) {
        b1[n] = *(const bf16x8*)(B1s + boffn[n] + koff[kk]);
        b3[n] = *(const bf16x8*)(B3s + boffn[n] + koff[kk]);
      }
#pragma unroll
      for (int m = 0; m < 4; ++m)
#pragma unroll
        for (int n = 0; n < 4; ++n) {
          acc1[m][n] = __builtin_amdgcn_mfma_f32_16x16x32_bf16(a[m], b1[n], acc1[m][n], 0, 0, 0);
          acc3[m][n] = __builtin_amdgcn_mfma_f32_16x16x32_bf16(a[m], b3[n], acc3[m][n], 0, 0, 0);
        }
    }
  }

#pragma unroll
  for (int m = 0; m < 4; ++m) {
    const int rb = m0 + wm * 64 + m * 16 + ((lane >> 4) << 2);
#pragma unroll
    for (int r2 = 0; r2 < 4; ++r2) {
      const int gr = rb + r2;
      if (gr >= ne) continue;
      bf16_t* orow = hbuf + (size_t)(hb + gr) * Hh + h0 + wn * 64 + (lane & 15);
#pragma unroll
      for (int n = 0; n < 4; ++n) {
        const float v1 = acc1[m][n][r2];
        const float v3 = acc3[m][n][r2];
        const float s = v1 / (1.f + __expf(-v1));
        orow[n * 16] = (__bf16)(s * v3);
      }
    }
  }
}

// ---------------- ffn2: out += (hbuf @ W2^T) * w_slot (atomic) --------------
__global__ __launch_bounds__(256, 3) void ffn2_kernel(
    const bf16_t* __restrict__ hbuf, const bf16_t* __restrict__ w2t,
    const int* __restrict__ perm, const int* __restrict__ counts,
    const int* __restrict__ offs, const int* __restrict__ ts,
    const float* __restrict__ topkw, float* __restrict__ out) {
  const int G = (Dd / 128) * NVT;
  const int orig = blockIdx.x;
  const int xcd = orig & 7, seq = orig >> 3;
  const int q = G >> 3, r = G & 7;
  const int lin = (xcd < r ? xcd * (q + 1) : r * (q + 1) + (xcd - r) * q) + seq;
  const int vt = lin % NVT;
  const int nb = lin / NVT;
  if (vt >= ts[Ee]) return;
  int e = 0;
#pragma unroll
  for (int i = 1; i < Ee; ++i) if (vt >= ts[i]) e = i;
  const int ne = counts[e];
  const int m0 = (vt - ts[e]) * 128;
  const int n0 = nb * 128;
  const int hb = offs[e];

  __shared__ __align__(16) bf16_t As[128 * 64];
  __shared__ __align__(16) bf16_t Bs[128 * 64];

  const int tid = threadIdx.x;
  const int lane = tid & 63;
  const int wid = tid >> 6;
  const int scol = ((tid & 7) << 3) ^ (((tid >> 3) & 7) << 3);
  uint32_t aoff[4], boff[4];
#pragma unroll
  for (int i = 0; i < 4; ++i) {
    const int row = i * 32 + (tid >> 3);
    int ar = hb + m0 + row;
    if (ar > 2 * Tt - 1) ar = 2 * Tt - 1;
    aoff[i] = (uint32_t)(ar * Hh + scol);
    boff[i] = (uint32_t)((n0 + row) * Hh + scol);
  }
  const bf16_t* w2e = w2t + (size_t)e * Dd * Hh;

  f32x4 acc[4][4];
#pragma unroll
  for (int m = 0; m < 4; ++m)
#pragma unroll
    for (int n = 0; n < 4; ++n) acc[m][n] = (f32x4){0.f, 0.f, 0.f, 0.f};

  const int wm = wid >> 1, wn = wid & 1;
  int aoffm[4], boffn[4], koff[2];
#pragma unroll
  for (int m = 0; m < 4; ++m) aoffm[m] = (wm * 64 + m * 16 + (lane & 15)) * 64;
#pragma unroll
  for (int n = 0; n < 4; ++n) boffn[n] = (wn * 64 + n * 16 + (lane & 15)) * 64;
#pragma unroll
  for (int kk = 0; kk < 2; ++kk)
    koff[kk] = (kk * 32 + (lane >> 4) * 8) ^ ((lane & 7) << 3);

  for (int kt = 0; kt < Hh / 64; ++kt) {
    const int k0 = kt * 64;
    __syncthreads();
#pragma unroll
    for (int i = 0; i < 4; ++i) {
      const int lb = (i * 256 + tid) * 8;
      gload16(hbuf + aoff[i] + k0, As + lb);
      gload16(w2e + boff[i] + k0, Bs + lb);
    }
    WAIT_VM0();
    __syncthreads();
#pragma unroll
    for (int kk = 0; kk < 2; ++kk) {
      bf16x8 a[4], b[4];
#pragma unroll
      for (int m = 0; m < 4; ++m) a[m] = *(const bf16x8*)(As + aoffm[m] + koff[kk]);
#pragma unroll
      for (int n = 0; n < 4; ++n) b[n] = *(const bf16x8*)(Bs + boffn[n] + koff[kk]);
#pragma unroll
      for (int m = 0; m < 4; ++m)
#pragma unroll
        for (int n = 0; n < 4; ++n)
          acc[m][n] = __builtin_amdgcn_mfma_f32_16x16x32_bf16(a[m], b[n], acc[m][n], 0, 0, 0);
    }
  }

#pragma unroll
  for (int m = 0; m < 4; ++m) {
    const int rb = m0 + wm * 64 + m * 16 + ((lane >> 4) << 2);
#pragma unroll
    for (int r2 = 0; r2 < 4; ++r2) {
      const int gr = rb + r2;
      if (gr >= ne) continue;
      const int rec = perm[e * Tt + gr];
      const float wgt = topkw[rec];
      float* orow = out + (size_t)(rec >> 1) * Dd + n0 + wn * 64 + (lane & 15);
#pragma unroll
      for (int n = 0; n < 4; ++n) atomicAdd(&orow[n * 16], wgt * acc[m][n][r2]);
    }
  }
}

extern "C" void kernel_launch(void* const* d_in, const int* in_sizes, int n_in,
                              void* d_out, int out_size, void* d_ws, size_t ws_size,
                              hipStream_t stream) {
  const float* x = (const float*)d_in[0];
  const float* gate_w = (const float*)d_in[1];
  const float* w1 = (const float*)d_in[2];
  const float* w2 = (const float*)d_in[3];
  const float* w3 = (const float*)d_in[4];
  float* out = (float*)d_out;

  char* ws = (char*)d_ws;
  size_t off = 0;
  auto alloc = [&](size_t b) { size_t r = off; off += (b + 255) & ~(size_t)255; return r; };
  float* topkw   = (float*)(ws + alloc((size_t)Tt * 2 * 4));
  int* counts    = (int*)(ws + alloc(Ee * 4));
  int* offs      = (int*)(ws + alloc((Ee + 1) * 4));
  int* ts        = (int*)(ws + alloc((Ee + 1) * 4));
  int* perm      = (int*)(ws + alloc((size_t)Ee * Tt * 4));
  bf16_t* xb     = (bf16_t*)(ws + alloc((size_t)Tt * Dd * 2));
  bf16_t* w1t    = (bf16_t*)(ws + alloc((size_t)Ee * Hh * Dd * 2));
  bf16_t* w3t    = (bf16_t*)(ws + alloc((size_t)Ee * Hh * Dd * 2));
  bf16_t* w2t    = (bf16_t*)(ws + alloc((size_t)Ee * Dd * Hh * 2));
  bf16_t* hbuf   = (bf16_t*)(ws + alloc((size_t)Tt * 2 * Hh * 2));
  if (ws_size < off) return;

  hipMemsetAsync(counts, 0, Ee * 4, stream);
  hipMemsetAsync(out, 0, (size_t)out_size * 4, stream);
  gate_prep13_kernel<<<128 + 2 * NTILE, 256, 0, stream>>>(
      x, gate_w, w1, w3, counts, perm, topkw, xb, w1t, w3t);
  scan_kernel<<<1, 64, 0, stream>>>(counts, offs, ts);
  ffn1_prep2_kernel<<<FFN1_BLKS + NTILE, 256, 0, stream>>>(
      xb, w1t, w3t, w2, perm, counts, offs, ts, hbuf, w2t);
  ffn2_kernel<<<(Dd / 128) * NVT, 256, 0, stream>>>(hbuf, w2t, perm, counts, offs, ts, topkw, out);
}

// Round 12
// 299.154 us; speedup vs baseline: 1.0555x; 1.0555x over previous
//
#include <hip/hip_runtime.h>
#include <hip/hip_bf16.h>
#include <cstdint>
#include <cstddef>

// MoE: T=4096, D=1024, H=2816, E=8, top-2, SwiGLU.
// R12: byte-identical resubmit of R11 (container died before measurement).
//      R9 (proven 294.6us) + split-K=2 ffn2 (1136 blocks, 2 obuf slices
//      aliased over dead w1t/w3t) + 4-way combine.

#define Tt 4096
#define Dd 1024
#define Hh 2816
#define Ee 8
#define NVT 71            // max sum_e ceil(ne/128)
#define NTILE 5632        // Ee*(Dd/64)*(Hh/64) per weight matrix
#define FFN1_BLKS ((Hh / 128) * NVT)  // 1562

typedef __bf16 bf16_t;
typedef __bf16 bf16x4 __attribute__((ext_vector_type(4)));
typedef __bf16 bf16x8 __attribute__((ext_vector_type(8)));
typedef float f32x4 __attribute__((ext_vector_type(4)));

__device__ __forceinline__ void gload16(const void* g, void* l) {
  __builtin_amdgcn_global_load_lds(
      (__attribute__((address_space(1))) void*)(void*)(uintptr_t)g,
      (__attribute__((address_space(3))) void*)l, 16, 0, 0);
}
#define WAIT_VM0() asm volatile("s_waitcnt vmcnt(0)" ::: "memory")

// ---- prep tile role: 64x64 fp32 -> bf16 transposed, via LDS (pitch 68) ----
__device__ __forceinline__ void prep_tile(const float* __restrict__ src,
                                          bf16_t* __restrict__ dst, int R, int C,
                                          int tbid, bf16_t* tile, int tid) {
  const int tilesC = C / 64, tilesR = R / 64;
  const int e = tbid / (tilesR * tilesC);
  const int rem = tbid % (tilesR * tilesC);
  const int r0 = (rem / tilesC) * 64, c0 = (rem % tilesC) * 64;
  src += (size_t)e * R * C;
  dst += (size_t)e * R * C;
  const int rr0 = tid >> 4;
  const int c4 = (tid & 15) * 4;
#pragma unroll
  for (int i = 0; i < 4; ++i) {
    const int r = rr0 + i * 16;
    const float4 v = *(const float4*)(src + (size_t)(r0 + r) * C + c0 + c4);
    tile[(c4 + 0) * 68 + r] = (__bf16)v.x;
    tile[(c4 + 1) * 68 + r] = (__bf16)v.y;
    tile[(c4 + 2) * 68 + r] = (__bf16)v.z;
    tile[(c4 + 3) * 68 + r] = (__bf16)v.w;
  }
  __syncthreads();
  const int rch = (tid & 7) * 8;
#pragma unroll
  for (int i = 0; i < 2; ++i) {
    const int c = (tid >> 3) + i * 32;
    const uint2 lo = *(const uint2*)(tile + c * 68 + rch);
    const uint2 hi = *(const uint2*)(tile + c * 68 + rch + 4);
    uint4 val; val.x = lo.x; val.y = lo.y; val.z = hi.x; val.w = hi.y;
    *(uint4*)(dst + (size_t)(c0 + c) * R + r0 + rch) = val;
  }
}

// ---------------- K1: gate (blocks 0..127) || prep w1/w3 -------------------
__global__ __launch_bounds__(256) void gate_prep13_kernel(
    const float* __restrict__ x, const float* __restrict__ gw_g,
    const float* __restrict__ w1, const float* __restrict__ w3,
    int* __restrict__ counts, int* __restrict__ perm, float* __restrict__ topkw,
    bf16_t* __restrict__ xb, bf16_t* __restrict__ w1t, bf16_t* __restrict__ w3t) {
  __shared__ __align__(16) char smem[Dd * 9 * 4];  // 36864B; prep uses 8704B
  const int tid = threadIdx.x;
  const int bid = blockIdx.x;
  if (bid >= 128) {
    const int pbid = bid - 128;
    bf16_t* tile = (bf16_t*)smem;
    if (pbid < NTILE) prep_tile(w1, w1t, Dd, Hh, pbid, tile, tid);
    else prep_tile(w3, w3t, Dd, Hh, pbid - NTILE, tile, tid);
    return;
  }
  float* gw = (float*)smem;
  for (int i = tid; i < Dd * Ee; i += 256) gw[(i >> 3) * 9 + (i & 7)] = gw_g[i];
  __syncthreads();
  const int tok = bid * 32 + (tid >> 3);
  const int part = tid & 7;
  const float* xr = x + (size_t)tok * Dd;
  float acc[Ee];
#pragma unroll
  for (int e = 0; e < Ee; ++e) acc[e] = 0.f;
  for (int i = 0; i < 32; ++i) {
    const int d = i * 32 + part * 4;
    const float4 xv = *(const float4*)(xr + d);
    bf16x4 bv; bv[0] = (__bf16)xv.x; bv[1] = (__bf16)xv.y; bv[2] = (__bf16)xv.z; bv[3] = (__bf16)xv.w;
    *(bf16x4*)(xb + (size_t)tok * Dd + d) = bv;
    const float xs[4] = {xv.x, xv.y, xv.z, xv.w};
#pragma unroll
    for (int j = 0; j < 4; ++j)
#pragma unroll
      for (int e = 0; e < Ee; ++e) acc[e] += xs[j] * gw[(d + j) * 9 + e];
  }
#pragma unroll
  for (int s = 1; s < 8; s <<= 1)
#pragma unroll
    for (int e = 0; e < Ee; ++e) acc[e] += __shfl_xor(acc[e], s, 64);
  if (part == 0) {
    int i0 = 0; float v0 = acc[0];
#pragma unroll
    for (int e = 1; e < Ee; ++e) if (acc[e] > v0) { v0 = acc[e]; i0 = e; }
    int i1 = -1; float v1 = -1e30f;
#pragma unroll
    for (int e = 0; e < Ee; ++e)
      if (e != i0 && acc[e] > v1) { v1 = acc[e]; i1 = e; }
    const float w0 = 1.f / (1.f + __expf(v1 - v0));
    topkw[tok * 2 + 0] = w0;
    topkw[tok * 2 + 1] = 1.f - w0;
    const int p0 = atomicAdd(&counts[i0], 1);
    perm[i0 * Tt + p0] = tok * 2 + 0;
    const int p1 = atomicAdd(&counts[i1], 1);
    perm[i1 * Tt + p1] = tok * 2 + 1;
  }
}

__global__ void scan_kernel(const int* __restrict__ counts, int* __restrict__ offs,
                            int* __restrict__ ts) {
  if (threadIdx.x == 0) {
    int s = 0, t = 0;
    for (int e = 0; e < Ee; ++e) {
      offs[e] = s; ts[e] = t;
      s += counts[e]; t += (counts[e] + 127) >> 7;
    }
    offs[Ee] = s; ts[Ee] = t;
  }
}

// ---------------- K3: fused ffn1 (blocks 0..1561) || prep w2 ----------------
__global__ __launch_bounds__(256, 2) void ffn1_prep2_kernel(
    const bf16_t* __restrict__ xb, const bf16_t* __restrict__ w1t,
    const bf16_t* __restrict__ w3t, const float* __restrict__ w2,
    const int* __restrict__ perm, const int* __restrict__ counts,
    const int* __restrict__ offs, const int* __restrict__ ts,
    bf16_t* __restrict__ hbuf, bf16_t* __restrict__ w2t) {
  __shared__ __align__(16) char smem[3 * 128 * 64 * 2];  // 49152B
  const int tid = threadIdx.x;
  const int obid = blockIdx.x;
  if (obid >= FFN1_BLKS) {
    prep_tile(w2, w2t, Hh, Dd, obid - FFN1_BLKS, (bf16_t*)smem, tid);
    return;
  }
  bf16_t* As = (bf16_t*)smem;
  bf16_t* B1s = As + 128 * 64;
  bf16_t* B3s = B1s + 128 * 64;

  const int G = FFN1_BLKS;
  const int xcd = obid & 7, seq = obid >> 3;
  const int q = G >> 3, r = G & 7;
  const int lin = (xcd < r ? xcd * (q + 1) : r * (q + 1) + (xcd - r) * q) + seq;
  const int vt = lin % NVT;
  const int nb = lin / NVT;
  if (vt >= ts[Ee]) return;
  int e = 0;
#pragma unroll
  for (int i = 1; i < Ee; ++i) if (vt >= ts[i]) e = i;
  const int ne = counts[e];
  const int m0 = (vt - ts[e]) * 128;
  const int h0 = nb * 128;
  const int hb = offs[e];

  const int lane = tid & 63;
  const int wid = tid >> 6;

  const int scol = ((tid & 7) << 3) ^ (((tid >> 3) & 7) << 3);
  uint32_t aoff[4], boff[4];
#pragma unroll
  for (int i = 0; i < 4; ++i) {
    const int row = i * 32 + (tid >> 3);
    const int gr = m0 + row;
    const int rec = (gr < ne) ? perm[e * Tt + gr] : 0;
    aoff[i] = (uint32_t)((rec >> 1) * Dd + scol);
    boff[i] = (uint32_t)((h0 + row) * Dd + scol);
  }
  const bf16_t* w1e = w1t + (size_t)e * Hh * Dd;
  const bf16_t* w3e = w3t + (size_t)e * Hh * Dd;

  f32x4 acc1[4][4], acc3[4][4];
#pragma unroll
  for (int m = 0; m < 4; ++m)
#pragma unroll
    for (int n = 0; n < 4; ++n) {
      acc1[m][n] = (f32x4){0.f, 0.f, 0.f, 0.f};
      acc3[m][n] = (f32x4){0.f, 0.f, 0.f, 0.f};
    }

  const int wm = wid >> 1, wn = wid & 1;
  int aoffm[4], boffn[4], koff[2];
#pragma unroll
  for (int m = 0; m < 4; ++m) aoffm[m] = (wm * 64 + m * 16 + (lane & 15)) * 64;
#pragma unroll
  for (int n = 0; n < 4; ++n) boffn[n] = (wn * 64 + n * 16 + (lane & 15)) * 64;
#pragma unroll
  for (int kk = 0; kk < 2; ++kk)
    koff[kk] = (kk * 32 + (lane >> 4) * 8) ^ ((lane & 7) << 3);

  for (int kt = 0; kt < Dd / 64; ++kt) {
    const int d0 = kt * 64;
    __syncthreads();
#pragma unroll
    for (int i = 0; i < 4; ++i) {
      const int lb = (i * 256 + tid) * 8;
      gload16(xb + aoff[i] + d0, As + lb);
      gload16(w1e + boff[i] + d0, B1s + lb);
      gload16(w3e + boff[i] + d0, B3s + lb);
    }
    WAIT_VM0();
    __syncthreads();
#pragma unroll
    for (int kk = 0; kk < 2; ++kk) {
      bf16x8 a[4], b1[4], b3[4];
#pragma unroll
      for (int m = 0; m < 4; ++m) a[m] = *(const bf16x8*)(As + aoffm[m] + koff[kk]);
#pragma unroll
      for (int n = 0; n < 4; ++n) {
        b1[n] = *(const bf16x8*)(B1s + boffn[n] + koff[kk]);
        b3[n] = *(const bf16x8*)(B3s + boffn[n] + koff[kk]);
      }
#pragma unroll
      for (int m = 0; m < 4; ++m)
#pragma unroll
        for (int n = 0; n < 4; ++n) {
          acc1[m][n] = __builtin_amdgcn_mfma_f32_16x16x32_bf16(a[m], b1[n], acc1[m][n], 0, 0, 0);
          acc3[m][n] = __builtin_amdgcn_mfma_f32_16x16x32_bf16(a[m], b3[n], acc3[m][n], 0, 0, 0);
        }
    }
  }

#pragma unroll
  for (int m = 0; m < 4; ++m) {
    const int rb = m0 + wm * 64 + m * 16 + ((lane >> 4) << 2);
#pragma unroll
    for (int r2 = 0; r2 < 4; ++r2) {
      const int gr = rb + r2;
      if (gr >= ne) continue;
      bf16_t* orow = hbuf + (size_t)(hb + gr) * Hh + h0 + wn * 64 + (lane & 15);
#pragma unroll
      for (int n = 0; n < 4; ++n) {
        const float v1 = acc1[m][n][r2];
        const float v3 = acc3[m][n][r2];
        const float s = v1 / (1.f + __expf(-v1));
        orow[n * 16] = (__bf16)(s * v3);
      }
    }
  }
}

// ---------------- ffn2: oslice[ks] = (h @ W2[kslice]) * w_slot, split-K=2 ---
__global__ __launch_bounds__(256, 3) void ffn2_kernel(
    const bf16_t* __restrict__ hbuf, const bf16_t* __restrict__ w2t,
    const int* __restrict__ perm, const int* __restrict__ counts,
    const int* __restrict__ offs, const int* __restrict__ ts,
    const float* __restrict__ topkw, float* __restrict__ obuf2) {
  const int G = (Dd / 128) * NVT * 2;  // 1136
  const int orig = blockIdx.x;
  const int xcd = orig & 7, seq = orig >> 3;
  const int q = G >> 3, r = G & 7;
  const int lin = (xcd < r ? xcd * (q + 1) : r * (q + 1) + (xcd - r) * q) + seq;
  const int vt = lin % NVT;
  const int nb = (lin / NVT) & 7;
  const int ks = lin / (NVT * 8);
  if (vt >= ts[Ee]) return;
  int e = 0;
#pragma unroll
  for (int i = 1; i < Ee; ++i) if (vt >= ts[i]) e = i;
  const int ne = counts[e];
  const int m0 = (vt - ts[e]) * 128;
  const int n0 = nb * 128;
  const int hb = offs[e];

  __shared__ __align__(16) bf16_t As[128 * 64];
  __shared__ __align__(16) bf16_t Bs[128 * 64];

  const int tid = threadIdx.x;
  const int lane = tid & 63;
  const int wid = tid >> 6;
  const int scol = ((tid & 7) << 3) ^ (((tid >> 3) & 7) << 3);
  uint32_t aoff[4], boff[4];
#pragma unroll
  for (int i = 0; i < 4; ++i) {
    const int row = i * 32 + (tid >> 3);
    int ar = hb + m0 + row;
    if (ar > 2 * Tt - 1) ar = 2 * Tt - 1;
    aoff[i] = (uint32_t)(ar * Hh + scol);
    boff[i] = (uint32_t)((n0 + row) * Hh + scol);
  }
  const bf16_t* w2e = w2t + (size_t)e * Dd * Hh;

  f32x4 acc[4][4];
#pragma unroll
  for (int m = 0; m < 4; ++m)
#pragma unroll
    for (int n = 0; n < 4; ++n) acc[m][n] = (f32x4){0.f, 0.f, 0.f, 0.f};

  const int wm = wid >> 1, wn = wid & 1;
  int aoffm[4], boffn[4], koff[2];
#pragma unroll
  for (int m = 0; m < 4; ++m) aoffm[m] = (wm * 64 + m * 16 + (lane & 15)) * 64;
#pragma unroll
  for (int n = 0; n < 4; ++n) boffn[n] = (wn * 64 + n * 16 + (lane & 15)) * 64;
#pragma unroll
  for (int kk = 0; kk < 2; ++kk)
    koff[kk] = (kk * 32 + (lane >> 4) * 8) ^ ((lane & 7) << 3);

  const int nt = (Hh / 64) / 2;  // 22
  const int kbase = ks * nt;
  for (int kt = 0; kt < nt; ++kt) {
    const int k0 = (kbase + kt) * 64;
    __syncthreads();
#pragma unroll
    for (int i = 0; i < 4; ++i) {
      const int lb = (i * 256 + tid) * 8;
      gload16(hbuf + aoff[i] + k0, As + lb);
      gload16(w2e + boff[i] + k0, Bs + lb);
    }
    WAIT_VM0();
    __syncthreads();
#pragma unroll
    for (int kk = 0; kk < 2; ++kk) {
      bf16x8 a[4], b[4];
#pragma unroll
      for (int m = 0; m < 4; ++m) a[m] = *(const bf16x8*)(As + aoffm[m] + koff[kk]);
#pragma unroll
      for (int n = 0; n < 4; ++n) b[n] = *(const bf16x8*)(Bs + boffn[n] + koff[kk]);
#pragma unroll
      for (int m = 0; m < 4; ++m)
#pragma unroll
        for (int n = 0; n < 4; ++n)
          acc[m][n] = __builtin_amdgcn_mfma_f32_16x16x32_bf16(a[m], b[n], acc[m][n], 0, 0, 0);
    }
  }

  float* oslice = obuf2 + (size_t)ks * 2 * Tt * Dd;
#pragma unroll
  for (int m = 0; m < 4; ++m) {
    const int rb = m0 + wm * 64 + m * 16 + ((lane >> 4) << 2);
#pragma unroll
    for (int r2 = 0; r2 < 4; ++r2) {
      const int gr = rb + r2;
      if (gr >= ne) continue;
      const int rec = perm[e * Tt + gr];
      const float wgt = topkw[rec];
      float* orow = oslice + (size_t)rec * Dd + n0 + wn * 64 + (lane & 15);
#pragma unroll
      for (int n = 0; n < 4; ++n) orow[n * 16] = wgt * acc[m][n][r2];
    }
  }
}

// ---------------- combine: out[t] = sum over 2 slots x 2 K-slices ----------
__global__ __launch_bounds__(256) void combine_kernel(const float* __restrict__ obuf2,
                                                      float* __restrict__ out) {
  const int t = blockIdx.x;
  const int d = threadIdx.x * 4;
  const float* s0 = obuf2;
  const float* s1 = obuf2 + (size_t)2 * Tt * Dd;
  const float4 a = *(const float4*)(s0 + (size_t)(2 * t) * Dd + d);
  const float4 b = *(const float4*)(s0 + (size_t)(2 * t + 1) * Dd + d);
  const float4 c = *(const float4*)(s1 + (size_t)(2 * t) * Dd + d);
  const float4 e = *(const float4*)(s1 + (size_t)(2 * t + 1) * Dd + d);
  float4 o;
  o.x = a.x + b.x + c.x + e.x; o.y = a.y + b.y + c.y + e.y;
  o.z = a.z + b.z + c.z + e.z; o.w = a.w + b.w + c.w + e.w;
  *(float4*)(out + (size_t)t * Dd + d) = o;
}

extern "C" void kernel_launch(void* const* d_in, const int* in_sizes, int n_in,
                              void* d_out, int out_size, void* d_ws, size_t ws_size,
                              hipStream_t stream) {
  const float* x = (const float*)d_in[0];
  const float* gate_w = (const float*)d_in[1];
  const float* w1 = (const float*)d_in[2];
  const float* w2 = (const float*)d_in[3];
  const float* w3 = (const float*)d_in[4];
  float* out = (float*)d_out;

  char* ws = (char*)d_ws;
  size_t off = 0;
  auto alloc = [&](size_t b) { size_t r = off; off += (b + 255) & ~(size_t)255; return r; };
  float* topkw   = (float*)(ws + alloc((size_t)Tt * 2 * 4));
  int* counts    = (int*)(ws + alloc(Ee * 4));
  int* offs      = (int*)(ws + alloc((Ee + 1) * 4));
  int* ts        = (int*)(ws + alloc((Ee + 1) * 4));
  int* perm      = (int*)(ws + alloc((size_t)Ee * Tt * 4));
  bf16_t* xb     = (bf16_t*)(ws + alloc((size_t)Tt * Dd * 2));
  const size_t w1t_off = alloc((size_t)Ee * Hh * Dd * 2);
  bf16_t* w1t    = (bf16_t*)(ws + w1t_off);
  bf16_t* w3t    = (bf16_t*)(ws + alloc((size_t)Ee * Hh * Dd * 2));
  bf16_t* w2t    = (bf16_t*)(ws + alloc((size_t)Ee * Dd * Hh * 2));
  bf16_t* hbuf   = (bf16_t*)(ws + alloc((size_t)Tt * 2 * Hh * 2));
  // obuf2 (2 slices x 8192 x 1024 f32 = 64MB) aliases dead w1t+w3t (92MB)
  float* obuf2   = (float*)(ws + w1t_off);
  if (ws_size < off) return;

  hipMemsetAsync(counts, 0, Ee * 4, stream);
  gate_prep13_kernel<<<128 + 2 * NTILE, 256, 0, stream>>>(
      x, gate_w, w1, w3, counts, perm, topkw, xb, w1t, w3t);
  scan_kernel<<<1, 64, 0, stream>>>(counts, offs, ts);
  ffn1_prep2_kernel<<<FFN1_BLKS + NTILE, 256, 0, stream>>>(
      xb, w1t, w3t, w2, perm, counts, offs, ts, hbuf, w2t);
  ffn2_kernel<<<(Dd / 128) * NVT * 2, 256, 0, stream>>>(
      hbuf, w2t, perm, counts, offs, ts, topkw, obuf2);
  combine_kernel<<<Tt, 256, 0, stream>>>(obuf2, out);
}

// Round 13
// 294.174 us; speedup vs baseline: 1.0734x; 1.0169x over previous
//
#include <hip/hip_runtime.h>
#include <hip/hip_bf16.h>
#include <cstdint>
#include <cstddef>

// MoE: T=4096, D=1024, H=2816, E=8, top-2, SwiGLU.
// R13: exact R9 structure (proven 294.6us) + prep_tile LDS pitch 68->66
//      (write bank conflict 4-way -> 2-way(free), read 2-way(free)).
//      ffn2 split-K reverted (R12 measured it -4.6us net).

#define Tt 4096
#define Dd 1024
#define Hh 2816
#define Ee 8
#define NVT 71            // max sum_e ceil(ne/128)
#define NTILE 5632        // Ee*(Dd/64)*(Hh/64) per weight matrix
#define FFN1_BLKS ((Hh / 128) * NVT)  // 1562
#define TP 66             // prep LDS pitch: 2-way (free) banks both sides

typedef __bf16 bf16_t;
typedef __bf16 bf16x4 __attribute__((ext_vector_type(4)));
typedef __bf16 bf16x8 __attribute__((ext_vector_type(8)));
typedef float f32x4 __attribute__((ext_vector_type(4)));

__device__ __forceinline__ void gload16(const void* g, void* l) {
  __builtin_amdgcn_global_load_lds(
      (__attribute__((address_space(1))) void*)(void*)(uintptr_t)g,
      (__attribute__((address_space(3))) void*)l, 16, 0, 0);
}
#define WAIT_VM0() asm volatile("s_waitcnt vmcnt(0)" ::: "memory")

// ---- prep tile role: 64x64 fp32 -> bf16 transposed, via LDS (pitch 66) ----
__device__ __forceinline__ void prep_tile(const float* __restrict__ src,
                                          bf16_t* __restrict__ dst, int R, int C,
                                          int tbid, bf16_t* tile, int tid) {
  const int tilesC = C / 64, tilesR = R / 64;
  const int e = tbid / (tilesR * tilesC);
  const int rem = tbid % (tilesR * tilesC);
  const int r0 = (rem / tilesC) * 64, c0 = (rem % tilesC) * 64;
  src += (size_t)e * R * C;
  dst += (size_t)e * R * C;
  const int rr0 = tid >> 4;
  const int c4 = (tid & 15) * 4;
#pragma unroll
  for (int i = 0; i < 4; ++i) {
    const int r = rr0 + i * 16;
    const float4 v = *(const float4*)(src + (size_t)(r0 + r) * C + c0 + c4);
    tile[(c4 + 0) * TP + r] = (__bf16)v.x;
    tile[(c4 + 1) * TP + r] = (__bf16)v.y;
    tile[(c4 + 2) * TP + r] = (__bf16)v.z;
    tile[(c4 + 3) * TP + r] = (__bf16)v.w;
  }
  __syncthreads();
  const int rch = (tid & 7) * 8;
#pragma unroll
  for (int i = 0; i < 2; ++i) {
    const int c = (tid >> 3) + i * 32;
    const uint2 lo = *(const uint2*)(tile + c * TP + rch);
    const uint2 hi = *(const uint2*)(tile + c * TP + rch + 4);
    uint4 val; val.x = lo.x; val.y = lo.y; val.z = hi.x; val.w = hi.y;
    *(uint4*)(dst + (size_t)(c0 + c) * R + r0 + rch) = val;
  }
}

// ---------------- K1: gate (blocks 0..127) || prep w1/w3 -------------------
__global__ __launch_bounds__(256) void gate_prep13_kernel(
    const float* __restrict__ x, const float* __restrict__ gw_g,
    const float* __restrict__ w1, const float* __restrict__ w3,
    int* __restrict__ counts, int* __restrict__ perm, float* __restrict__ topkw,
    bf16_t* __restrict__ xb, bf16_t* __restrict__ w1t, bf16_t* __restrict__ w3t) {
  __shared__ __align__(16) char smem[Dd * 9 * 4];  // 36864B; prep uses 64*TP*2
  const int tid = threadIdx.x;
  const int bid = blockIdx.x;
  if (bid >= 128) {
    const int pbid = bid - 128;
    bf16_t* tile = (bf16_t*)smem;
    if (pbid < NTILE) prep_tile(w1, w1t, Dd, Hh, pbid, tile, tid);
    else prep_tile(w3, w3t, Dd, Hh, pbid - NTILE, tile, tid);
    return;
  }
  float* gw = (float*)smem;
  for (int i = tid; i < Dd * Ee; i += 256) gw[(i >> 3) * 9 + (i & 7)] = gw_g[i];
  __syncthreads();
  const int tok = bid * 32 + (tid >> 3);
  const int part = tid & 7;
  const float* xr = x + (size_t)tok * Dd;
  float acc[Ee];
#pragma unroll
  for (int e = 0; e < Ee; ++e) acc[e] = 0.f;
  for (int i = 0; i < 32; ++i) {
    const int d = i * 32 + part * 4;
    const float4 xv = *(const float4*)(xr + d);
    bf16x4 bv; bv[0] = (__bf16)xv.x; bv[1] = (__bf16)xv.y; bv[2] = (__bf16)xv.z; bv[3] = (__bf16)xv.w;
    *(bf16x4*)(xb + (size_t)tok * Dd + d) = bv;
    const float xs[4] = {xv.x, xv.y, xv.z, xv.w};
#pragma unroll
    for (int j = 0; j < 4; ++j)
#pragma unroll
      for (int e = 0; e < Ee; ++e) acc[e] += xs[j] * gw[(d + j) * 9 + e];
  }
#pragma unroll
  for (int s = 1; s < 8; s <<= 1)
#pragma unroll
    for (int e = 0; e < Ee; ++e) acc[e] += __shfl_xor(acc[e], s, 64);
  if (part == 0) {
    int i0 = 0; float v0 = acc[0];
#pragma unroll
    for (int e = 1; e < Ee; ++e) if (acc[e] > v0) { v0 = acc[e]; i0 = e; }
    int i1 = -1; float v1 = -1e30f;
#pragma unroll
    for (int e = 0; e < Ee; ++e)
      if (e != i0 && acc[e] > v1) { v1 = acc[e]; i1 = e; }
    const float w0 = 1.f / (1.f + __expf(v1 - v0));
    topkw[tok * 2 + 0] = w0;
    topkw[tok * 2 + 1] = 1.f - w0;
    const int p0 = atomicAdd(&counts[i0], 1);
    perm[i0 * Tt + p0] = tok * 2 + 0;
    const int p1 = atomicAdd(&counts[i1], 1);
    perm[i1 * Tt + p1] = tok * 2 + 1;
  }
}

__global__ void scan_kernel(const int* __restrict__ counts, int* __restrict__ offs,
                            int* __restrict__ ts) {
  if (threadIdx.x == 0) {
    int s = 0, t = 0;
    for (int e = 0; e < Ee; ++e) {
      offs[e] = s; ts[e] = t;
      s += counts[e]; t += (counts[e] + 127) >> 7;
    }
    offs[Ee] = s; ts[Ee] = t;
  }
}

// ---------------- K3: fused ffn1 (blocks 0..1561) || prep w2 ----------------
__global__ __launch_bounds__(256, 2) void ffn1_prep2_kernel(
    const bf16_t* __restrict__ xb, const bf16_t* __restrict__ w1t,
    const bf16_t* __restrict__ w3t, const float* __restrict__ w2,
    const int* __restrict__ perm, const int* __restrict__ counts,
    const int* __restrict__ offs, const int* __restrict__ ts,
    bf16_t* __restrict__ hbuf, bf16_t* __restrict__ w2t) {
  __shared__ __align__(16) char smem[3 * 128 * 64 * 2];  // 49152B
  const int tid = threadIdx.x;
  const int obid = blockIdx.x;
  if (obid >= FFN1_BLKS) {
    prep_tile(w2, w2t, Hh, Dd, obid - FFN1_BLKS, (bf16_t*)smem, tid);
    return;
  }
  bf16_t* As = (bf16_t*)smem;
  bf16_t* B1s = As + 128 * 64;
  bf16_t* B3s = B1s + 128 * 64;

  const int G = FFN1_BLKS;
  const int xcd = obid & 7, seq = obid >> 3;
  const int q = G >> 3, r = G & 7;
  const int lin = (xcd < r ? xcd * (q + 1) : r * (q + 1) + (xcd - r) * q) + seq;
  const int vt = lin % NVT;
  const int nb = lin / NVT;
  if (vt >= ts[Ee]) return;
  int e = 0;
#pragma unroll
  for (int i = 1; i < Ee; ++i) if (vt >= ts[i]) e = i;
  const int ne = counts[e];
  const int m0 = (vt - ts[e]) * 128;
  const int h0 = nb * 128;
  const int hb = offs[e];

  const int lane = tid & 63;
  const int wid = tid >> 6;

  const int scol = ((tid & 7) << 3) ^ (((tid >> 3) & 7) << 3);
  uint32_t aoff[4], boff[4];
#pragma unroll
  for (int i = 0; i < 4; ++i) {
    const int row = i * 32 + (tid >> 3);
    const int gr = m0 + row;
    const int rec = (gr < ne) ? perm[e * Tt + gr] : 0;
    aoff[i] = (uint32_t)((rec >> 1) * Dd + scol);
    boff[i] = (uint32_t)((h0 + row) * Dd + scol);
  }
  const bf16_t* w1e = w1t + (size_t)e * Hh * Dd;
  const bf16_t* w3e = w3t + (size_t)e * Hh * Dd;

  f32x4 acc1[4][4], acc3[4][4];
#pragma unroll
  for (int m = 0; m < 4; ++m)
#pragma unroll
    for (int n = 0; n < 4; ++n) {
      acc1[m][n] = (f32x4){0.f, 0.f, 0.f, 0.f};
      acc3[m][n] = (f32x4){0.f, 0.f, 0.f, 0.f};
    }

  const int wm = wid >> 1, wn = wid & 1;
  int aoffm[4], boffn[4], koff[2];
#pragma unroll
  for (int m = 0; m < 4; ++m) aoffm[m] = (wm * 64 + m * 16 + (lane & 15)) * 64;
#pragma unroll
  for (int n = 0; n < 4; ++n) boffn[n] = (wn * 64 + n * 16 + (lane & 15)) * 64;
#pragma unroll
  for (int kk = 0; kk < 2; ++kk)
    koff[kk] = (kk * 32 + (lane >> 4) * 8) ^ ((lane & 7) << 3);

  for (int kt = 0; kt < Dd / 64; ++kt) {
    const int d0 = kt * 64;
    __syncthreads();
#pragma unroll
    for (int i = 0; i < 4; ++i) {
      const int lb = (i * 256 + tid) * 8;
      gload16(xb + aoff[i] + d0, As + lb);
      gload16(w1e + boff[i] + d0, B1s + lb);
      gload16(w3e + boff[i] + d0, B3s + lb);
    }
    WAIT_VM0();
    __syncthreads();
#pragma unroll
    for (int kk = 0; kk < 2; ++kk) {
      bf16x8 a[4], b1[4], b3[4];
#pragma unroll
      for (int m = 0; m < 4; ++m) a[m] = *(const bf16x8*)(As + aoffm[m] + koff[kk]);
#pragma unroll
      for (int n = 0; n < 4; ++n) {
        b1[n] = *(const bf16x8*)(B1s + boffn[n] + koff[kk]);
        b3[n] = *(const bf16x8*)(B3s + boffn[n] + koff[kk]);
      }
#pragma unroll
      for (int m = 0; m < 4; ++m)
#pragma unroll
        for (int n = 0; n < 4; ++n) {
          acc1[m][n] = __builtin_amdgcn_mfma_f32_16x16x32_bf16(a[m], b1[n], acc1[m][n], 0, 0, 0);
          acc3[m][n] = __builtin_amdgcn_mfma_f32_16x16x32_bf16(a[m], b3[n], acc3[m][n], 0, 0, 0);
        }
    }
  }

#pragma unroll
  for (int m = 0; m < 4; ++m) {
    const int rb = m0 + wm * 64 + m * 16 + ((lane >> 4) << 2);
#pragma unroll
    for (int r2 = 0; r2 < 4; ++r2) {
      const int gr = rb + r2;
      if (gr >= ne) continue;
      bf16_t* orow = hbuf + (size_t)(hb + gr) * Hh + h0 + wn * 64 + (lane & 15);
#pragma unroll
      for (int n = 0; n < 4; ++n) {
        const float v1 = acc1[m][n][r2];
        const float v3 = acc3[m][n][r2];
        const float s = v1 / (1.f + __expf(-v1));
        orow[n * 16] = (__bf16)(s * v3);
      }
    }
  }
}

// ---------------- ffn2: obuf = (hbuf @ W2^T) * w_slot -----------------------
__global__ __launch_bounds__(256, 3) void ffn2_kernel(
    const bf16_t* __restrict__ hbuf, const bf16_t* __restrict__ w2t,
    const int* __restrict__ perm, const int* __restrict__ counts,
    const int* __restrict__ offs, const int* __restrict__ ts,
    const float* __restrict__ topkw, float* __restrict__ obuf) {
  const int G = (Dd / 128) * NVT;  // 568
  const int orig = blockIdx.x;
  const int xcd = orig & 7, seq = orig >> 3;
  const int q = G >> 3, r = G & 7;
  const int lin = (xcd < r ? xcd * (q + 1) : r * (q + 1) + (xcd - r) * q) + seq;
  const int vt = lin % NVT;
  const int nb = lin / NVT;
  if (vt >= ts[Ee]) return;
  int e = 0;
#pragma unroll
  for (int i = 1; i < Ee; ++i) if (vt >= ts[i]) e = i;
  const int ne = counts[e];
  const int m0 = (vt - ts[e]) * 128;
  const int n0 = nb * 128;
  const int hb = offs[e];

  __shared__ __align__(16) bf16_t As[128 * 64];
  __shared__ __align__(16) bf16_t Bs[128 * 64];

  const int tid = threadIdx.x;
  const int lane = tid & 63;
  const int wid = tid >> 6;
  const int scol = ((tid & 7) << 3) ^ (((tid >> 3) & 7) << 3);
  uint32_t aoff[4], boff[4];
#pragma unroll
  for (int i = 0; i < 4; ++i) {
    const int row = i * 32 + (tid >> 3);
    int ar = hb + m0 + row;
    if (ar > 2 * Tt - 1) ar = 2 * Tt - 1;
    aoff[i] = (uint32_t)(ar * Hh + scol);
    boff[i] = (uint32_t)((n0 + row) * Hh + scol);
  }
  const bf16_t* w2e = w2t + (size_t)e * Dd * Hh;

  f32x4 acc[4][4];
#pragma unroll
  for (int m = 0; m < 4; ++m)
#pragma unroll
    for (int n = 0; n < 4; ++n) acc[m][n] = (f32x4){0.f, 0.f, 0.f, 0.f};

  const int wm = wid >> 1, wn = wid & 1;
  int aoffm[4], boffn[4], koff[2];
#pragma unroll
  for (int m = 0; m < 4; ++m) aoffm[m] = (wm * 64 + m * 16 + (lane & 15)) * 64;
#pragma unroll
  for (int n = 0; n < 4; ++n) boffn[n] = (wn * 64 + n * 16 + (lane & 15)) * 64;
#pragma unroll
  for (int kk = 0; kk < 2; ++kk)
    koff[kk] = (kk * 32 + (lane >> 4) * 8) ^ ((lane & 7) << 3);

  for (int kt = 0; kt < Hh / 64; ++kt) {
    const int k0 = kt * 64;
    __syncthreads();
#pragma unroll
    for (int i = 0; i < 4; ++i) {
      const int lb = (i * 256 + tid) * 8;
      gload16(hbuf + aoff[i] + k0, As + lb);
      gload16(w2e + boff[i] + k0, Bs + lb);
    }
    WAIT_VM0();
    __syncthreads();
#pragma unroll
    for (int kk = 0; kk < 2; ++kk) {
      bf16x8 a[4], b[4];
#pragma unroll
      for (int m = 0; m < 4; ++m) a[m] = *(const bf16x8*)(As + aoffm[m] + koff[kk]);
#pragma unroll
      for (int n = 0; n < 4; ++n) b[n] = *(const bf16x8*)(Bs + boffn[n] + koff[kk]);
#pragma unroll
      for (int m = 0; m < 4; ++m)
#pragma unroll
        for (int n = 0; n < 4; ++n)
          acc[m][n] = __builtin_amdgcn_mfma_f32_16x16x32_bf16(a[m], b[n], acc[m][n], 0, 0, 0);
    }
  }

#pragma unroll
  for (int m = 0; m < 4; ++m) {
    const int rb = m0 + wm * 64 + m * 16 + ((lane >> 4) << 2);
#pragma unroll
    for (int r2 = 0; r2 < 4; ++r2) {
      const int gr = rb + r2;
      if (gr >= ne) continue;
      const int rec = perm[e * Tt + gr];
      const float wgt = topkw[rec];
      float* orow = obuf + (size_t)rec * Dd + n0 + wn * 64 + (lane & 15);
#pragma unroll
      for (int n = 0; n < 4; ++n) orow[n * 16] = wgt * acc[m][n][r2];
    }
  }
}

// ---------------- combine: out[t] = obuf[2t] + obuf[2t+1] -------------------
__global__ __launch_bounds__(256) void combine_kernel(const float* __restrict__ obuf,
                                                      float* __restrict__ out) {
  const int t = blockIdx.x;
  const int d = threadIdx.x * 4;
  const float4 a = *(const float4*)(obuf + (size_t)(2 * t) * Dd + d);
  const float4 b = *(const float4*)(obuf + (size_t)(2 * t + 1) * Dd + d);
  float4 o;
  o.x = a.x + b.x; o.y = a.y + b.y; o.z = a.z + b.z; o.w = a.w + b.w;
  *(float4*)(out + (size_t)t * Dd + d) = o;
}

extern "C" void kernel_launch(void* const* d_in, const int* in_sizes, int n_in,
                              void* d_out, int out_size, void* d_ws, size_t ws_size,
                              hipStream_t stream) {
  const float* x = (const float*)d_in[0];
  const float* gate_w = (const float*)d_in[1];
  const float* w1 = (const float*)d_in[2];
  const float* w2 = (const float*)d_in[3];
  const float* w3 = (const float*)d_in[4];
  float* out = (float*)d_out;

  char* ws = (char*)d_ws;
  size_t off = 0;
  auto alloc = [&](size_t b) { size_t r = off; off += (b + 255) & ~(size_t)255; return r; };
  float* topkw   = (float*)(ws + alloc((size_t)Tt * 2 * 4));
  int* counts    = (int*)(ws + alloc(Ee * 4));
  int* offs      = (int*)(ws + alloc((Ee + 1) * 4));
  int* ts        = (int*)(ws + alloc((Ee + 1) * 4));
  int* perm      = (int*)(ws + alloc((size_t)Ee * Tt * 4));
  bf16_t* xb     = (bf16_t*)(ws + alloc((size_t)Tt * Dd * 2));
  const size_t w1t_off = alloc((size_t)Ee * Hh * Dd * 2);
  bf16_t* w1t    = (bf16_t*)(ws + w1t_off);
  bf16_t* w3t    = (bf16_t*)(ws + alloc((size_t)Ee * Hh * Dd * 2));
  bf16_t* w2t    = (bf16_t*)(ws + alloc((size_t)Ee * Dd * Hh * 2));
  bf16_t* hbuf   = (bf16_t*)(ws + alloc((size_t)Tt * 2 * Hh * 2));
  // obuf (8192 x 1024 f32 = 32MB) aliases w1t (dead during ffn2/combine)
  float* obuf    = (float*)(ws + w1t_off);
  if (ws_size < off) return;

  hipMemsetAsync(counts, 0, Ee * 4, stream);
  gate_prep13_kernel<<<128 + 2 * NTILE, 256, 0, stream>>>(
      x, gate_w, w1, w3, counts, perm, topkw, xb, w1t, w3t);
  scan_kernel<<<1, 64, 0, stream>>>(counts, offs, ts);
  ffn1_prep2_kernel<<<FFN1_BLKS + NTILE, 256, 0, stream>>>(
      xb, w1t, w3t, w2, perm, counts, offs, ts, hbuf, w2t);
  ffn2_kernel<<<(Dd / 128) * NVT, 256, 0, stream>>>(
      hbuf, w2t, perm, counts, offs, ts, topkw, obuf);
  combine_kernel<<<Tt, 256, 0, stream>>>(obuf, out);
}